// Round 3
// baseline (229.455 us; speedup 1.0000x reference)
//
#include <hip/hip_runtime.h>
#include <stdint.h>

#define NN 100000
#define NE 1600000
#define DD 128
#define NTILES ((NN + 127) / 128)   // 782
#define NB 512                      // phase-A blocks
#define CHUNK (NE / NB)             // 3125
#define NBUCK ((NN + 255) / 256)    // 391 coarse buckets (dst>>8)

typedef __bf16 bf16x8 __attribute__((ext_vector_type(8)));
typedef float f32x4 __attribute__((ext_vector_type(4)));
typedef float f32x2 __attribute__((ext_vector_type(2)));

// round-to-nearest-even fp32 -> bf16, two at a time, packed into a uint
__device__ __forceinline__ unsigned int f2bf2(float a, float b) {
  union { float f; unsigned u; } x, y;
  x.f = a; y.f = b;
  unsigned ua = x.u + (0x7FFFu + ((x.u >> 16) & 1u));
  unsigned ub = y.u + (0x7FFFu + ((y.u >> 16) & 1u));
  return (ua >> 16) | (ub & 0xFFFF0000u);
}

// ---------------- 00. zero hist + cursors (workspace arrives poisoned) ------
__global__ __launch_bounds__(256) void zero_kernel(int* __restrict__ p) {
  int t = blockIdx.x * 256 + threadIdx.x;
  if (t < 2 * NBUCK) p[t] = 0;
}

// ---------------- 0+A1. h -> h8 (fp8) + hbf (bf16 fragment order) + hist ----
// Block b covers rows b*16 .. b*16+15 (6250*16 = 100,000 exactly).
// Thread t: row m = t>>4 (local), chunk c8 = t&15 (8 floats).
// Fragment slot for global row R, chunk c8: tile = R>>7, rt = (R>>4)&7 = b&7,
// m = R&15, kc = c8>>2, quad = c8&3.
// Blocks < NB additionally histogram their 3125-edge chunk into the global
// 391-entry bucket histogram (LDS-aggregated, then ~391 global atomics).
__global__ __launch_bounds__(256) void convert_kernel(
    const float4* __restrict__ hp, uint2* __restrict__ h8,
    uint4* __restrict__ hbf, const int* __restrict__ dst,
    int* __restrict__ ghist) {
  __shared__ int lh[NBUCK];
  int t = threadIdx.x, b = blockIdx.x;
  int gid = b * 256 + t;                       // 1.6M threads, 8 floats each
  float4 a = hp[2 * gid], c = hp[2 * gid + 1];
  int lo = __builtin_amdgcn_cvt_pk_fp8_f32(a.x, a.y, 0, false);
  lo = __builtin_amdgcn_cvt_pk_fp8_f32(a.z, a.w, lo, true);
  int hi = __builtin_amdgcn_cvt_pk_fp8_f32(c.x, c.y, 0, false);
  hi = __builtin_amdgcn_cvt_pk_fp8_f32(c.z, c.w, hi, true);
  h8[gid] = make_uint2((unsigned)lo, (unsigned)hi);

  uint4 q;
  q.x = f2bf2(a.x, a.y);
  q.y = f2bf2(a.z, a.w);
  q.z = f2bf2(c.x, c.y);
  q.w = f2bf2(c.z, c.w);
  int m = t >> 4, c8 = t & 15;
  int rt = b & 7, kc = c8 >> 2, quad = c8 & 3;
  hbf[(size_t)(b >> 3) * 2048 + (((rt << 2) + kc) << 6) + (quad << 4) + m] = q;

  if (b < NB) {   // block-uniform branch: __syncthreads inside is safe
    for (int i = t; i < NBUCK; i += 256) lh[i] = 0;
    __syncthreads();
    int e0 = b * CHUNK;
    for (int e = e0 + t; e < e0 + CHUNK; e += 256)
      atomicAdd(&lh[dst[e] >> 8], 1);
    __syncthreads();
    for (int i = t; i < NBUCK; i += 256)
      if (lh[i]) atomicAdd(&ghist[i], lh[i]);
  }
}

// ---------------- A3. coarse scatter: internal scan + atomic reservation ----
// Each block: local bucket hist of its chunk, dual LDS scan (local counts for
// LDS layout + global hist for bucket bases), one atomicAdd per non-empty
// bucket to reserve a contiguous range, LDS-stage, ordered burst writeback.
__global__ __launch_bounds__(256) void coarse_scatter_kernel(
    const int* __restrict__ src, const int* __restrict__ dst,
    const int* __restrict__ ghist, int* __restrict__ gcur,
    unsigned* __restrict__ ebuf) {
  __shared__ int lhp[512];    // local hist -> inclusive scan
  __shared__ int gbp[512];    // global hist -> inclusive scan
  __shared__ int lbase[NBUCK];
  __shared__ int lcur[NBUCK];
  __shared__ int gstart[NBUCK];
  __shared__ unsigned sdata[CHUNK];
  __shared__ int sgpos[CHUNK];
  int t = threadIdx.x, b = blockIdx.x;
  lhp[t] = 0;
  lhp[t + 256] = 0;
  gbp[t] = (t < NBUCK) ? ghist[t] : 0;
  gbp[t + 256] = (t + 256 < NBUCK) ? ghist[t + 256] : 0;
  __syncthreads();
  int e0 = b * CHUNK;
  for (int e = e0 + t; e < e0 + CHUNK; e += 256)
    atomicAdd(&lhp[dst[e] >> 8], 1);
  __syncthreads();
  int c0 = lhp[t], c1 = lhp[t + 256];
  int g0 = gbp[t], g1 = gbp[t + 256];
  for (int d = 1; d < 512; d <<= 1) {
    int x0 = (t >= d) ? lhp[t - d] : 0;
    int x1 = ((t + 256) >= d) ? lhp[t + 256 - d] : 0;
    int y0 = (t >= d) ? gbp[t - d] : 0;
    int y1 = ((t + 256) >= d) ? gbp[t + 256 - d] : 0;
    __syncthreads();
    lhp[t] += x0; lhp[t + 256] += x1;
    gbp[t] += y0; gbp[t + 256] += y1;
    __syncthreads();
  }
  if (t < NBUCK) {
    lbase[t] = lhp[t] - c0;
    lcur[t] = 0;
    int resv = c0 ? atomicAdd(&gcur[t], c0) : 0;
    gstart[t] = (gbp[t] - g0) + resv;          // bucket base (exclusive) + slice
  }
  int i2 = t + 256;
  if (i2 < NBUCK) {
    lbase[i2] = lhp[i2] - c1;
    lcur[i2] = 0;
    int resv = c1 ? atomicAdd(&gcur[i2], c1) : 0;
    gstart[i2] = (gbp[i2] - g1) + resv;
  }
  __syncthreads();
  for (int e = e0 + t; e < e0 + CHUNK; e += 256) {
    int d = dst[e], s = src[e];
    int bk = d >> 8;
    int slot = atomicAdd(&lcur[bk], 1);
    int lp = lbase[bk] + slot;
    sdata[lp] = ((unsigned)(d & 255) << 24) | (unsigned)s;
    sgpos[lp] = gstart[bk] + slot;
  }
  __syncthreads();
  for (int j = t; j < CHUNK; j += 256) ebuf[sgpos[j]] = sdata[j];
}

// ---------------- B. fine sort within bucket -> csr + offs ------------------
// Bucket base re-derived internally by scanning the 391-entry global hist.
__global__ __launch_bounds__(256) void fine_sort_kernel(
    const unsigned* __restrict__ ebuf, const int* __restrict__ ghist,
    int* __restrict__ csr, int* __restrict__ offs) {
  __shared__ int gbp[512];
  __shared__ int hist[256], scn[256], cur[256];
  int t = threadIdx.x, g = blockIdx.x;
  gbp[t] = (t < NBUCK) ? ghist[t] : 0;
  gbp[t + 256] = (t + 256 < NBUCK) ? ghist[t + 256] : 0;
  hist[t] = 0;
  __syncthreads();
  for (int d = 1; d < 512; d <<= 1) {
    int y0 = (t >= d) ? gbp[t - d] : 0;
    int y1 = ((t + 256) >= d) ? gbp[t + 256 - d] : 0;
    __syncthreads();
    gbp[t] += y0; gbp[t + 256] += y1;
    __syncthreads();
  }
  int end = gbp[g];                 // inclusive scan at g
  int base = end - ghist[g];        // exclusive
  for (int j = base + t; j < end; j += 256)
    atomicAdd(&hist[ebuf[j] >> 24], 1);
  __syncthreads();
  int v = hist[t];
  scn[t] = v;
  __syncthreads();
  for (int d = 1; d < 256; d <<= 1) {
    int x = (t >= d) ? scn[t - d] : 0;
    __syncthreads();
    scn[t] += x;
    __syncthreads();
  }
  int excl = scn[t] - v;
  int node = g * 256 + t;
  if (node < NN) offs[node] = base + excl;
  if (node == NN - 1) offs[NN] = NE;
  cur[t] = excl;
  __syncthreads();
  for (int j = base + t; j < end; j += 256) {
    unsigned p = ebuf[j];
    int pos = atomicAdd(&cur[p >> 24], 1);
    csr[base + pos] = (int)(p & 0x00FFFFFFu);
  }
}

// ---------------- fp8 accumulate helper -------------------------------------
__device__ __forceinline__ void acc16(float* a, uint4 u) {
  f32x2 p;
  p = __builtin_amdgcn_cvt_pk_f32_fp8(u.x, false); a[0] += p.x;  a[1] += p.y;
  p = __builtin_amdgcn_cvt_pk_f32_fp8(u.x, true);  a[2] += p.x;  a[3] += p.y;
  p = __builtin_amdgcn_cvt_pk_f32_fp8(u.y, false); a[4] += p.x;  a[5] += p.y;
  p = __builtin_amdgcn_cvt_pk_f32_fp8(u.y, true);  a[6] += p.x;  a[7] += p.y;
  p = __builtin_amdgcn_cvt_pk_f32_fp8(u.z, false); a[8] += p.x;  a[9] += p.y;
  p = __builtin_amdgcn_cvt_pk_f32_fp8(u.z, true);  a[10] += p.x; a[11] += p.y;
  p = __builtin_amdgcn_cvt_pk_f32_fp8(u.w, false); a[12] += p.x; a[13] += p.y;
  p = __builtin_amdgcn_cvt_pk_f32_fp8(u.w, true);  a[14] += p.x; a[15] += p.y;
}

// ---------------- 4. gather-mean -> bf16 in MFMA-fragment-linear order ------
__global__ __launch_bounds__(256) void gather_frag_kernel(
    const uint4* __restrict__ h8, const int* __restrict__ offs,
    const int* __restrict__ csr, uint4* __restrict__ hfrag) {
  int q = (blockIdx.x * 256 + threadIdx.x) >> 3;   // 0 .. NTILES*128-1 (exact)
  int l = threadIdx.x & 7;                         // 16B chunk within fp8 row
  float a[16];
#pragma unroll
  for (int i = 0; i < 16; i++) a[i] = 0.f;
  float sc = 0.f;
  if (q < NN) {
    int off0 = offs[q], off1 = offs[q + 1];
    int j = off0;
    for (; j + 4 <= off1; j += 4) {
      int s0 = csr[j], s1 = csr[j + 1], s2 = csr[j + 2], s3 = csr[j + 3];
      uint4 u0 = h8[(size_t)s0 * 8 + l];
      uint4 u1 = h8[(size_t)s1 * 8 + l];
      uint4 u2 = h8[(size_t)s2 * 8 + l];
      uint4 u3 = h8[(size_t)s3 * 8 + l];
      acc16(a, u0); acc16(a, u1); acc16(a, u2); acc16(a, u3);
    }
    for (; j < off1; j++) acc16(a, h8[(size_t)csr[j] * 8 + l]);
    int deg = off1 - off0;
    sc = (deg > 0) ? (1.0f / (float)deg) : 0.0f;
  }
  uint4 r0, r1;
  r0.x = f2bf2(a[0] * sc, a[1] * sc);   r0.y = f2bf2(a[2] * sc, a[3] * sc);
  r0.z = f2bf2(a[4] * sc, a[5] * sc);   r0.w = f2bf2(a[6] * sc, a[7] * sc);
  r1.x = f2bf2(a[8] * sc, a[9] * sc);   r1.y = f2bf2(a[10] * sc, a[11] * sc);
  r1.z = f2bf2(a[12] * sc, a[13] * sc); r1.w = f2bf2(a[14] * sc, a[15] * sc);
  int r = q & 127;
  int rt = r >> 4, m = r & 15;
  int kc = l >> 1, quad = (l & 1) << 1;
  int slot = (((rt << 2) + kc) << 6) + (quad << 4) + m;
  uint4* base = hfrag + (size_t)(q >> 7) * 2048;
  base[slot] = r0;
  base[slot + 16] = r1;
}

// ---------------- W staging into fragment-linear LDS ------------------------
__device__ __forceinline__ void stage_w(const float* __restrict__ X,
                                        uint4* buf, int t) {
#pragma unroll
  for (int i = 0; i < 8; i++) {
    int id = t + (i << 8);     // 0..2047
    int r = id >> 4;           // 0..127
    int c8 = id & 15;          // 0..15
    const float4* p = (const float4*)(X + (size_t)r * DD + (c8 << 3));
    float4 v0 = p[0], v1 = p[1];
    uint4 q;
    q.x = f2bf2(v0.x, v0.y);
    q.y = f2bf2(v0.z, v0.w);
    q.z = f2bf2(v1.x, v1.y);
    q.w = f2bf2(v1.z, v1.w);
    int rt = r >> 4, m = r & 15, kc = c8 >> 2, quad = c8 & 3;
    buf[(((rt << 2) + kc) << 6) + (quad << 4) + m] = q;
  }
}

__device__ __forceinline__ void compute_reg(const uint4* a, const uint4* sWb,
                                            f32x4 acc[2][8], int lane) {
#pragma unroll
  for (int kc = 0; kc < 4; kc++) {
    bf16x8 bfr[8];
#pragma unroll
    for (int n = 0; n < 8; n++)
      bfr[n] = *(const bf16x8*)&sWb[(((n << 2) + kc) << 6) + lane];
    bf16x8 a0 = *(const bf16x8*)&a[kc];
    bf16x8 a1 = *(const bf16x8*)&a[4 + kc];
#pragma unroll
    for (int n = 0; n < 8; n++) {
      acc[0][n] = __builtin_amdgcn_mfma_f32_16x16x32_bf16(a0, bfr[n], acc[0][n], 0, 0, 0);
      acc[1][n] = __builtin_amdgcn_mfma_f32_16x16x32_bf16(a1, bfr[n], acc[1][n], 0, 0, 0);
    }
  }
}

// ---------------- 5. out = h@Ws^T + hneigh@Wn^T + b -------------------------
// Both A operands arrive fragment-ordered in HBM (hbf from convert, hfrag from
// gather) -> loaded straight to registers, fully coalesced. Only W goes
// through LDS; single barrier; 128 back-to-back MFMAs.
// Last-tile rows >= NN read uninitialized hbf -> garbage accs, guarded out.
__global__ __launch_bounds__(256, 2) void gemm_kernel(
    const uint4* __restrict__ hbf, const uint4* __restrict__ hfrag,
    const float* __restrict__ Wself, const float* __restrict__ Wneigh,
    const float* __restrict__ bias, float* __restrict__ out) {
  __shared__ uint4 sW[4096];   // [0,2048) Wself, [2048,4096) Wneigh; 64 KB
  int t = threadIdx.x;
  int wv = t >> 6;
  int lane = t & 63;
  int row0 = blockIdx.x * 128;

  const uint4* fb1 = hbf + (size_t)blockIdx.x * 2048;
  const uint4* fb2 = hfrag + (size_t)blockIdx.x * 2048;
  uint4 a1[8], a2[8];
#pragma unroll
  for (int kc = 0; kc < 4; kc++) {
    int s0 = ((((wv * 2 + 0) << 2) + kc) << 6) + lane;
    int s1 = ((((wv * 2 + 1) << 2) + kc) << 6) + lane;
    a1[kc] = fb1[s0]; a1[4 + kc] = fb1[s1];
    a2[kc] = fb2[s0]; a2[4 + kc] = fb2[s1];
  }

  stage_w(Wself, sW, t);
  stage_w(Wneigh, sW + 2048, t);

  f32x4 acc[2][8];
#pragma unroll
  for (int i = 0; i < 2; i++)
#pragma unroll
    for (int n = 0; n < 8; n++) acc[i][n] = f32x4{0.f, 0.f, 0.f, 0.f};

  __syncthreads();
  compute_reg(a1, sW, acc, lane);
  compute_reg(a2, sW + 2048, acc, lane);

  // epilogue: + bias (C/D layout: col=lane&15, row=(lane>>4)*4+reg)
  int col = lane & 15, rq = lane >> 4;
  float bv[8];
#pragma unroll
  for (int n = 0; n < 8; n++) bv[n] = bias[n * 16 + col];
#pragma unroll
  for (int rt = 0; rt < 2; rt++) {
    int rb = row0 + (wv * 2 + rt) * 16 + rq * 4;
#pragma unroll
    for (int r = 0; r < 4; r++) {
      int row = rb + r;
      if (row < NN) {
        float* op = out + (size_t)row * DD + col;
#pragma unroll
        for (int n = 0; n < 8; n++) op[n * 16] = acc[rt][n][r] + bv[n];
      }
    }
  }
}

extern "C" void kernel_launch(void* const* d_in, const int* in_sizes, int n_in,
                              void* d_out, int out_size, void* d_ws, size_t ws_size,
                              hipStream_t stream) {
  const float* h      = (const float*)d_in[0];
  const int*   src    = (const int*)d_in[1];
  const int*   dst    = (const int*)d_in[2];
  const float* Wself  = (const float*)d_in[3];
  const float* Wneigh = (const float*)d_in[4];
  const float* bias   = (const float*)d_in[5];
  float* out = (float*)d_out;

  // workspace layout (bytes); ebuf aliases hfrag head (dead before gather).
  char* ws = (char*)d_ws;
  unsigned* h8       = (unsigned*)ws;                     // 12,800,000
  unsigned* hbf      = (unsigned*)(ws + 12800000);        // 25,624,576 (782*32768)
  unsigned* hfrag    = (unsigned*)(ws + 38424576);        // 25,624,576
  unsigned* ebuf     = (unsigned*)(ws + 38424576);        //  6,400,000 (alias)
  int*      csr      = (int*)(ws + 64049152);             //  6,400,000
  int*      offs     = (int*)(ws + 70449152);             //    400,016
  int*      ghist    = (int*)(ws + 70849168);             //      1,564
  int*      gcur     = (int*)(ws + 70850732);             //      1,564

  zero_kernel<<<(2 * NBUCK + 255) / 256, 256, 0, stream>>>(ghist);
  convert_kernel<<<6250, 256, 0, stream>>>((const float4*)h, (uint2*)h8,
                                           (uint4*)hbf, dst, ghist);
  coarse_scatter_kernel<<<NB, 256, 0, stream>>>(src, dst, ghist, gcur, ebuf);
  fine_sort_kernel<<<NBUCK, 256, 0, stream>>>(ebuf, ghist, csr, offs);
  gather_frag_kernel<<<(NTILES * 128) / 32, 256, 0, stream>>>(
      (const uint4*)h8, offs, csr, (uint4*)hfrag);
  gemm_kernel<<<NTILES, 256, 0, stream>>>((const uint4*)hbf, (const uint4*)hfrag,
                                          Wself, Wneigh, bias, out);
}